// Round 8
// baseline (237.988 us; speedup 1.0000x reference)
//
#include <hip/hip_runtime.h>

#define NUM_E 1024
#define DIM 64
#define NROWS 65536                  // 64*32*32
#define OUT0_SIZE 4194304            // 64*64*32*32
#define OUT1_OFF OUT0_SIZE
#define LOSS_OFF (OUT0_SIZE + 65536) // 4259840
#define KSPLIT 4
#define KCHUNK (NUM_E / KSPLIT)      // 256 codes per wave-slice
#define G 8                          // codes processed per outer iteration

// ---------------- prep: En_k = np.sum(e_k*e_k) in numpy pairwise order ----
__device__ __forceinline__ float np_sumsq64_arr(const float* __restrict__ x) {
#pragma clang fp contract(off)
    float r[8];
#pragma unroll
    for (int j = 0; j < 8; ++j) r[j] = x[j] * x[j];
#pragma unroll
    for (int i = 8; i < 64; i += 8) {
#pragma unroll
        for (int j = 0; j < 8; ++j) {
            float p = x[i + j] * x[i + j];
            r[j] = r[j] + p;
        }
    }
    return ((r[0] + r[1]) + (r[2] + r[3])) + ((r[4] + r[5]) + (r[6] + r[7]));
}

__global__ __launch_bounds__(256) void vq_prep_kernel(const float* __restrict__ e,
                                                      float* __restrict__ En,
                                                      float* __restrict__ out) {
    const int k = blockIdx.x * 256 + threadIdx.x;   // grid covers 1024 exactly
    if (k == 0) out[LOSS_OFF] = 0.0f;               // d_out re-poisoned every call
    float xr[DIM];
    const float4* ep = (const float4*)(e + (size_t)k * DIM);
#pragma unroll
    for (int i = 0; i < 16; ++i) {
        float4 v = ep[i];
        xr[4*i+0] = v.x; xr[4*i+1] = v.y; xr[4*i+2] = v.z; xr[4*i+3] = v.w;
    }
    En[k] = np_sumsq64_arr(xr);
}

// ---------------- fused scan+finish ----------------
// Block = 256 threads = 4 waves over 64 rows; wave q scans codes
// [q*256,(q+1)*256). Inner loop: 8 codes at a time, 8 independent FMA chains
// (hides 4-cyc FMA latency from a single wave; R7 was dependent-chain-bound
// at 2.75 waves/SIMD -> 72% VALU). One uniform base pointer per 8-code group;
// e reads are s_load base+imm. Per-k d-order is strictly 0..63 sequential ->
// bit-exact vs the np/sgemm reference (validated R3).
#define SQ8(A, B)                                              \
    { float p;                                                 \
      p = A.x*A.x; r0 = r0 + p;  p = A.y*A.y; r1 = r1 + p;     \
      p = A.z*A.z; r2 = r2 + p;  p = A.w*A.w; r3 = r3 + p;     \
      p = B.x*B.x; r4 = r4 + p;  p = B.y*B.y; r5 = r5 + p;     \
      p = B.z*B.z; r6 = r6 + p;  p = B.w*B.w; r7 = r7 + p; }

// One float4 chunk C of the dot products for all 8 codes.
#define STEP(C, ZC)                                                         \
    { float4 a0 = eb[C], a1 = eb[C+16], a2 = eb[C+32], a3 = eb[C+48],       \
             a4 = eb[C+64], a5 = eb[C+80], a6 = eb[C+96], a7 = eb[C+112];   \
      m0=fmaf(a0.x,ZC.x,m0); m0=fmaf(a0.y,ZC.y,m0); m0=fmaf(a0.z,ZC.z,m0); m0=fmaf(a0.w,ZC.w,m0); \
      m1=fmaf(a1.x,ZC.x,m1); m1=fmaf(a1.y,ZC.y,m1); m1=fmaf(a1.z,ZC.z,m1); m1=fmaf(a1.w,ZC.w,m1); \
      m2=fmaf(a2.x,ZC.x,m2); m2=fmaf(a2.y,ZC.y,m2); m2=fmaf(a2.z,ZC.z,m2); m2=fmaf(a2.w,ZC.w,m2); \
      m3=fmaf(a3.x,ZC.x,m3); m3=fmaf(a3.y,ZC.y,m3); m3=fmaf(a3.z,ZC.z,m3); m3=fmaf(a3.w,ZC.w,m3); \
      m4=fmaf(a4.x,ZC.x,m4); m4=fmaf(a4.y,ZC.y,m4); m4=fmaf(a4.z,ZC.z,m4); m4=fmaf(a4.w,ZC.w,m4); \
      m5=fmaf(a5.x,ZC.x,m5); m5=fmaf(a5.y,ZC.y,m5); m5=fmaf(a5.z,ZC.z,m5); m5=fmaf(a5.w,ZC.w,m5); \
      m6=fmaf(a6.x,ZC.x,m6); m6=fmaf(a6.y,ZC.y,m6); m6=fmaf(a6.z,ZC.z,m6); m6=fmaf(a6.w,ZC.w,m6); \
      m7=fmaf(a7.x,ZC.x,m7); m7=fmaf(a7.y,ZC.y,m7); m7=fmaf(a7.z,ZC.z,m7); m7=fmaf(a7.w,ZC.w,m7); }

// Score + argmin update for code k+J (ascending J preserves first-index ties).
#define SCORE(J, MJ)                                           \
    { float s;                                                 \
      {                                                        \
        _Pragma("clang fp contract(off)")                      \
        float twoM = 2.0f * MJ;                                \
        float t = A - twoM;                                    \
        s = t + En[k + J];                                     \
      }                                                        \
      if (s < best) { best = s; bk = k + J; } }

#define EPI4(Q, ZQ)                                            \
    { float4 evv = erp[Q]; float df;                           \
      o0[(size_t)(4*Q+0)*1024] = evv.x; df = evv.x - ZQ.x; lsum = fmaf(df,df,lsum); \
      o0[(size_t)(4*Q+1)*1024] = evv.y; df = evv.y - ZQ.y; lsum = fmaf(df,df,lsum); \
      o0[(size_t)(4*Q+2)*1024] = evv.z; df = evv.z - ZQ.z; lsum = fmaf(df,df,lsum); \
      o0[(size_t)(4*Q+3)*1024] = evv.w; df = evv.w - ZQ.w; lsum = fmaf(df,df,lsum); }

__global__ __launch_bounds__(256, 4) void vq_fused_kernel(const float* __restrict__ z,
                                                          const float* __restrict__ e,
                                                          const float* __restrict__ En,
                                                          float* __restrict__ out) {
    const int lane = threadIdx.x & 63;
    const int q = __builtin_amdgcn_readfirstlane((int)(threadIdx.x >> 6)); // wave-uniform slice id
    const int n = blockIdx.x * 64 + lane;            // row

    float4 z0,z1,z2,z3,z4,z5,z6,z7,z8,z9,z10,z11,z12,z13,z14,z15;
    {
        const float4* zp = (const float4*)(z + (size_t)n * DIM);
        z0=zp[0]; z1=zp[1]; z2=zp[2]; z3=zp[3]; z4=zp[4]; z5=zp[5]; z6=zp[6]; z7=zp[7];
        z8=zp[8]; z9=zp[9]; z10=zp[10]; z11=zp[11]; z12=zp[12]; z13=zp[13]; z14=zp[14]; z15=zp[15];
    }

    // A = np pairwise sum of z*z (bit-exact vs numpy, validated R3)
    float A;
    {
#pragma clang fp contract(off)
        float r0,r1,r2,r3,r4,r5,r6,r7;
        { float p;
          p = z0.x*z0.x; r0 = p;  p = z0.y*z0.y; r1 = p;
          p = z0.z*z0.z; r2 = p;  p = z0.w*z0.w; r3 = p;
          p = z1.x*z1.x; r4 = p;  p = z1.y*z1.y; r5 = p;
          p = z1.z*z1.z; r6 = p;  p = z1.w*z1.w; r7 = p; }
        SQ8(z2,  z3)  SQ8(z4,  z5)  SQ8(z6,  z7)
        SQ8(z8,  z9)  SQ8(z10, z11) SQ8(z12, z13) SQ8(z14, z15)
        A = ((r0 + r1) + (r2 + r3)) + ((r4 + r5) + (r6 + r7));
    }

    const int k0 = q * KCHUNK;
    float best = 3.4e38f;
    int bk = k0;
#pragma unroll 1
    for (int kk = 0; kk < KCHUNK; kk += G) {
        const int k = k0 + kk;
        const float4* eb = (const float4*)(e + (size_t)k * DIM);  // uniform base -> s_load +imm
        float m0=0.f,m1=0.f,m2=0.f,m3=0.f,m4=0.f,m5=0.f,m6=0.f,m7=0.f;
        STEP(0,  z0)  STEP(1,  z1)  STEP(2,  z2)  STEP(3,  z3)
        STEP(4,  z4)  STEP(5,  z5)  STEP(6,  z6)  STEP(7,  z7)
        STEP(8,  z8)  STEP(9,  z9)  STEP(10, z10) STEP(11, z11)
        STEP(12, z12) STEP(13, z13) STEP(14, z14) STEP(15, z15)
        SCORE(0, m0) SCORE(1, m1) SCORE(2, m2) SCORE(3, m3)
        SCORE(4, m4) SCORE(5, m5) SCORE(6, m6) SCORE(7, m7)
    }

    __shared__ float ls[KSPLIT][64];
    __shared__ int   li[KSPLIT][64];
    ls[q][lane] = best;
    li[q][lane] = bk;
    __syncthreads();

    if (threadIdx.x < 64) {                              // wave 0 does the epilogue
        float b0 = ls[0][lane];
        int   kb = li[0][lane];
#pragma unroll
        for (int qq = 1; qq < KSPLIT; ++qq) {
            float sq = ls[qq][lane];
            if (sq < b0) { b0 = sq; kb = li[qq][lane]; } // ascending q = ascending k
        }

        const int b  = n >> 10;      // H*W = 1024
        const int hw = n & 1023;
        const float4* erp = (const float4*)(e + (size_t)kb * DIM);  // L2-hot gather
        float* o0 = out + (size_t)b * 65536 + hw;        // out0[b, d, hw]
        float lsum = 0.0f;
        EPI4(0,  z0)  EPI4(1,  z1)  EPI4(2,  z2)  EPI4(3,  z3)
        EPI4(4,  z4)  EPI4(5,  z5)  EPI4(6,  z6)  EPI4(7,  z7)
        EPI4(8,  z8)  EPI4(9,  z9)  EPI4(10, z10) EPI4(11, z11)
        EPI4(12, z12) EPI4(13, z13) EPI4(14, z14) EPI4(15, z15)
        out[OUT1_OFF + n] = (float)kb;

#pragma unroll
        for (int off = 32; off > 0; off >>= 1)
            lsum += __shfl_down(lsum, off, 64);
        if (lane == 0)
            atomicAdd(&out[LOSS_OFF], lsum * (1.25f / 4194304.0f));
    }
}

extern "C" void kernel_launch(void* const* d_in, const int* in_sizes, int n_in,
                              void* d_out, int out_size, void* d_ws, size_t ws_size,
                              hipStream_t stream) {
    const float* z = (const float*)d_in[0];       // [65536, 64] fp32
    const float* e = (const float*)d_in[1];       // [1024, 64] fp32
    float* out = (float*)d_out;
    float* En  = (float*)d_ws;                    // 1024 fp32 norms (4 KB)

    vq_prep_kernel<<<NUM_E / 256, 256, 0, stream>>>(e, En, out);
    vq_fused_kernel<<<NROWS / 64, 256, 0, stream>>>(z, e, En, out);
}

// Round 9
// 223.585 us; speedup vs baseline: 1.0644x; 1.0644x over previous
//
#include <hip/hip_runtime.h>

#define NUM_E 1024
#define DIM 64
#define NROWS 65536                  // 64*32*32
#define OUT0_SIZE 4194304            // 64*64*32*32
#define OUT1_OFF OUT0_SIZE
#define LOSS_OFF (OUT0_SIZE + 65536) // 4259840
#define KSPLIT 4
#define KCHUNK (NUM_E / KSPLIT)      // 256 codes per wave-slice

// ---------------- prep: En_k = np.sum(e_k*e_k) in numpy pairwise order ----
__device__ __forceinline__ float np_sumsq64_arr(const float* __restrict__ x) {
#pragma clang fp contract(off)
    float r[8];
#pragma unroll
    for (int j = 0; j < 8; ++j) r[j] = x[j] * x[j];
#pragma unroll
    for (int i = 8; i < 64; i += 8) {
#pragma unroll
        for (int j = 0; j < 8; ++j) {
            float p = x[i + j] * x[i + j];
            r[j] = r[j] + p;
        }
    }
    return ((r[0] + r[1]) + (r[2] + r[3])) + ((r[4] + r[5]) + (r[6] + r[7]));
}

__global__ __launch_bounds__(256) void vq_prep_kernel(const float* __restrict__ e,
                                                      float* __restrict__ En,
                                                      float* __restrict__ out) {
    const int k = blockIdx.x * 256 + threadIdx.x;   // grid covers 1024 exactly
    if (k == 0) out[LOSS_OFF] = 0.0f;               // d_out re-poisoned every call
    float xr[DIM];
    const float4* ep = (const float4*)(e + (size_t)k * DIM);
#pragma unroll
    for (int i = 0; i < 16; ++i) {
        float4 v = ep[i];
        xr[4*i+0] = v.x; xr[4*i+1] = v.y; xr[4*i+2] = v.z; xr[4*i+3] = v.w;
    }
    En[k] = np_sumsq64_arr(xr);
}

// ---------------- fused scan+finish ----------------
// Block = 256 threads = 4 waves over 64 rows; wave q scans codes
// [q*256,(q+1)*256). amdgpu_waves_per_eu(4,4) pins min=MAX occupancy at 4
// waves/EU: the allocator gets the full 128-VGPR budget and (theory) stops
// sinking the loop-invariant z loads into the k-loop (R4-R8: VGPR_Count
// 40-48, z re-loaded from L1 every k-iter, ~2x VALU overhead). G=1 keeps
// e's in-flight footprint at 64 floats so e stays SGPR-staged (s_load).
#define SQ8(A, B)                                              \
    { float p;                                                 \
      p = A.x*A.x; r0 = r0 + p;  p = A.y*A.y; r1 = r1 + p;     \
      p = A.z*A.z; r2 = r2 + p;  p = A.w*A.w; r3 = r3 + p;     \
      p = B.x*B.x; r4 = r4 + p;  p = B.y*B.y; r5 = r5 + p;     \
      p = B.z*B.z; r6 = r6 + p;  p = B.w*B.w; r7 = r7 + p; }

#define DOT4(Q, ZQ)                                            \
    { float4 ev = ep[Q];                                       \
      m = fmaf(ev.x, ZQ.x, m); m = fmaf(ev.y, ZQ.y, m);        \
      m = fmaf(ev.z, ZQ.z, m); m = fmaf(ev.w, ZQ.w, m); }

#define EPI4(Q, ZQ)                                            \
    { float4 evv = erp[Q]; float df;                           \
      o0[(size_t)(4*Q+0)*1024] = evv.x; df = evv.x - ZQ.x; lsum = fmaf(df,df,lsum); \
      o0[(size_t)(4*Q+1)*1024] = evv.y; df = evv.y - ZQ.y; lsum = fmaf(df,df,lsum); \
      o0[(size_t)(4*Q+2)*1024] = evv.z; df = evv.z - ZQ.z; lsum = fmaf(df,df,lsum); \
      o0[(size_t)(4*Q+3)*1024] = evv.w; df = evv.w - ZQ.w; lsum = fmaf(df,df,lsum); }

__global__
__attribute__((amdgpu_flat_work_group_size(256, 256), amdgpu_waves_per_eu(4, 4)))
void vq_fused_kernel(const float* __restrict__ z,
                     const float* __restrict__ e,
                     const float* __restrict__ En,
                     float* __restrict__ out) {
    const int lane = threadIdx.x & 63;
    const int q = __builtin_amdgcn_readfirstlane((int)(threadIdx.x >> 6)); // wave-uniform slice id
    const int n = blockIdx.x * 64 + lane;            // row

    float4 z0,z1,z2,z3,z4,z5,z6,z7,z8,z9,z10,z11,z12,z13,z14,z15;
    {
        const float4* zp = (const float4*)(z + (size_t)n * DIM);
        z0=zp[0]; z1=zp[1]; z2=zp[2]; z3=zp[3]; z4=zp[4]; z5=zp[5]; z6=zp[6]; z7=zp[7];
        z8=zp[8]; z9=zp[9]; z10=zp[10]; z11=zp[11]; z12=zp[12]; z13=zp[13]; z14=zp[14]; z15=zp[15];
    }

    // A = np pairwise sum of z*z (bit-exact vs numpy, validated R3)
    float A;
    {
#pragma clang fp contract(off)
        float r0,r1,r2,r3,r4,r5,r6,r7;
        { float p;
          p = z0.x*z0.x; r0 = p;  p = z0.y*z0.y; r1 = p;
          p = z0.z*z0.z; r2 = p;  p = z0.w*z0.w; r3 = p;
          p = z1.x*z1.x; r4 = p;  p = z1.y*z1.y; r5 = p;
          p = z1.z*z1.z; r6 = p;  p = z1.w*z1.w; r7 = p; }
        SQ8(z2,  z3)  SQ8(z4,  z5)  SQ8(z6,  z7)
        SQ8(z8,  z9)  SQ8(z10, z11) SQ8(z12, z13) SQ8(z14, z15)
        A = ((r0 + r1) + (r2 + r3)) + ((r4 + r5) + (r6 + r7));
    }

    const int k0 = q * KCHUNK;
    float best = 3.4e38f;
    int bk = k0;
#pragma unroll 1
    for (int kk = 0; kk < KCHUNK; ++kk) {
        const int k = k0 + kk;
        const float4* ep = (const float4*)(e + (size_t)k * DIM);  // uniform -> s_load
        float m = 0.0f;                                  // sequential sgemm chain
        DOT4(0,  z0)  DOT4(1,  z1)  DOT4(2,  z2)  DOT4(3,  z3)
        DOT4(4,  z4)  DOT4(5,  z5)  DOT4(6,  z6)  DOT4(7,  z7)
        DOT4(8,  z8)  DOT4(9,  z9)  DOT4(10, z10) DOT4(11, z11)
        DOT4(12, z12) DOT4(13, z13) DOT4(14, z14) DOT4(15, z15)
        float s;
        {
#pragma clang fp contract(off)
            float twoM = 2.0f * m;                       // exact
            float t = A - twoM;                          // the ref's rounding grid
            s = t + En[k];
        }
        if (s < best) { best = s; bk = k; }              // strict < => first index
    }

    __shared__ float ls[KSPLIT][64];
    __shared__ int   li[KSPLIT][64];
    ls[q][lane] = best;
    li[q][lane] = bk;
    __syncthreads();

    if (threadIdx.x < 64) {                              // wave 0 does the epilogue
        float b0 = ls[0][lane];
        int   kb = li[0][lane];
#pragma unroll
        for (int qq = 1; qq < KSPLIT; ++qq) {
            float sq = ls[qq][lane];
            if (sq < b0) { b0 = sq; kb = li[qq][lane]; } // ascending q = ascending k
        }

        const int b  = n >> 10;      // H*W = 1024
        const int hw = n & 1023;
        const float4* erp = (const float4*)(e + (size_t)kb * DIM);  // L2-hot gather
        float* o0 = out + (size_t)b * 65536 + hw;        // out0[b, d, hw]
        float lsum = 0.0f;
        EPI4(0,  z0)  EPI4(1,  z1)  EPI4(2,  z2)  EPI4(3,  z3)
        EPI4(4,  z4)  EPI4(5,  z5)  EPI4(6,  z6)  EPI4(7,  z7)
        EPI4(8,  z8)  EPI4(9,  z9)  EPI4(10, z10) EPI4(11, z11)
        EPI4(12, z12) EPI4(13, z13) EPI4(14, z14) EPI4(15, z15)
        out[OUT1_OFF + n] = (float)kb;

#pragma unroll
        for (int off = 32; off > 0; off >>= 1)
            lsum += __shfl_down(lsum, off, 64);
        if (lane == 0)
            atomicAdd(&out[LOSS_OFF], lsum * (1.25f / 4194304.0f));
    }
}

extern "C" void kernel_launch(void* const* d_in, const int* in_sizes, int n_in,
                              void* d_out, int out_size, void* d_ws, size_t ws_size,
                              hipStream_t stream) {
    const float* z = (const float*)d_in[0];       // [65536, 64] fp32
    const float* e = (const float*)d_in[1];       // [1024, 64] fp32
    float* out = (float*)d_out;
    float* En  = (float*)d_ws;                    // 1024 fp32 norms (4 KB)

    vq_prep_kernel<<<NUM_E / 256, 256, 0, stream>>>(e, En, out);
    vq_fused_kernel<<<NROWS / 64, 256, 0, stream>>>(z, e, En, out);
}